// Round 7
// baseline (130.464 us; speedup 1.0000x reference)
//
#include <hip/hip_runtime.h>
#include <stdint.h>

#define B_ROWS 4096
#define OUTF   1024
#define INF    1024
#define KTOT   3072          // 3 * 1024
#define BN_EPS 1e-5f
#define BM 128
#define BN 64
#define BK 64

typedef short  short8  __attribute__((ext_vector_type(8)));
typedef float  floatx4 __attribute__((ext_vector_type(4)));

struct alignas(8) s4 { short x, y, z, w; };

// s_waitcnt SIMM16 (gfx9/gfx950): vmcnt[3:0]=imm[3:0], expcnt=imm[6:4],
// lgkmcnt=imm[11:8], vmcnt[5:4]=imm[15:14].
#define WAIT_VM3 0x0F73      // vmcnt(3)
#define WAIT_VM0 0x0F70      // vmcnt(0)

__device__ __forceinline__ short f2bf(float f) {
  union { float f; uint32_t u; } cv; cv.f = f;
  uint32_t u = cv.u;
  uint32_t r = (u + 0x7fffu + ((u >> 16) & 1u)) >> 16;  // RNE
  return (short)r;
}

__device__ __forceinline__ float bf2f(unsigned short s) {
  union { uint32_t u; float f; } cv; cv.u = ((uint32_t)s) << 16;
  return cv.f;
}

__device__ __forceinline__ void load_lds16(const void* g, void* l) {
  __builtin_amdgcn_global_load_lds(
      (const __attribute__((address_space(1))) uint32_t*)(uintptr_t)g,
      (__attribute__((address_space(3))) uint32_t*)(uint32_t)(uintptr_t)l,
      16, 0, 0);
}

// ---- 1. prep: x -> bf16 {x,x^2,x^3} (Xb), c1|c2|c3 -> bf16 Wb --------------
// bias skipped: a per-column constant shifts the batch mean and is cancelled
// exactly by BatchNorm (variance unaffected).
__global__ void prep_all(const float4* __restrict__ x4,
                         const float4* __restrict__ c1, const float4* __restrict__ c2,
                         const float4* __restrict__ c3,
                         short* __restrict__ Xb, short* __restrict__ Wb) {
  int b = blockIdx.x;
  if (b < 4096) {
    int idx = b * 256 + threadIdx.x;           // 1,048,576 float4 of x
    float4 v = x4[idx];
    int row = idx >> 8;
    int c   = (idx & 255) << 2;
    size_t base = (size_t)row * KTOT + c;
    s4 p1 = { f2bf(v.x), f2bf(v.y), f2bf(v.z), f2bf(v.w) };
    float ax = v.x * v.x, ay = v.y * v.y, az = v.z * v.z, aw = v.w * v.w;
    s4 p2 = { f2bf(ax), f2bf(ay), f2bf(az), f2bf(aw) };
    s4 p3 = { f2bf(ax * v.x), f2bf(ay * v.y), f2bf(az * v.z), f2bf(aw * v.w) };
    *(s4*)&Xb[base]        = p1;
    *(s4*)&Xb[base + 1024] = p2;
    *(s4*)&Xb[base + 2048] = p3;
  } else {
    int idx = (b - 4096) * 256 + threadIdx.x;  // 262,144 float4 per weight
    int row = idx >> 8;
    int c   = (idx & 255) << 2;
    size_t base = (size_t)row * KTOT + c;
    float4 a = c1[idx], bb = c2[idx], d = c3[idx];
    s4 p1 = { f2bf(a.x),  f2bf(a.y),  f2bf(a.z),  f2bf(a.w)  };
    s4 p2 = { f2bf(bb.x), f2bf(bb.y), f2bf(bb.z), f2bf(bb.w) };
    s4 p3 = { f2bf(d.x),  f2bf(d.y),  f2bf(d.z),  f2bf(d.w)  };
    *(s4*)&Wb[base]        = p1;
    *(s4*)&Wb[base + 1024] = p2;
    *(s4*)&Wb[base + 2048] = p3;
  }
}

// ---- 2. GEMM 128x64 tiles, BK=64, 512 threads (8 waves), double-buffer -----
// R7 theory: R0/R1/R6 all pin the gemm at ~24.5us whenever the CU runs ONE
// barrier-lockstepped block (128 KB LDS). Cutting LDS traffic (R1 -40%,
// R6 -20%) did nothing -> not LDS-throughput-bound; the cost is the shared
// vmcnt+barrier sync with no independent work to fill it. Fix: 48 KB LDS
// (2x(16+8) KB dbuf) -> 2 blocks/CU, grid 512 -> two INDEPENDENT barrier
// domains per CU; block B's MFMAs cover block A's sync stalls (m97/m114
// composed model). Counted vmcnt kept via 2-barrier dbuf schedule:
//   { vmcnt(3); bar1; compute(buf t&1); bar2; stage(t+2)->buf t&1 }
// 3 loads/tile/thread, 2 tiles in flight, steady vmcnt(3), vmcnt(0) only
// at step 47. WAR-safe: stage target freed by bar2; waitcnt-before-bar1
// makes all waves' tile-t loads visible before any wave reads.
// Per-wave shape: 32x32 (R0-proven), wave grid 4x2. XOR chunk swizzle
// unchanged: physical 16B slot p of row r holds chunk p ^ (r&7) -> 0
// conflicts. Y written bf16 (R6-verified, absmax unchanged).
__global__ __launch_bounds__(512, 4) void gemm_poly(
    const short* __restrict__ Xb, const short* __restrict__ Wb,
    unsigned short* __restrict__ Yb, float* __restrict__ psum,
    float* __restrict__ psq) {
  __shared__ __align__(16) short As[2][BM * BK];   // 2 x 16 KB
  __shared__ __align__(16) short Bs[2][BN * BK];   // 2 x  8 KB  (48 KB total)
  const int tid  = threadIdx.x;
  const int lane = tid & 63;
  const int wave = tid >> 6;           // 0..7
  const int wr = wave >> 1;            // 0..3 : 32-row group
  const int wc = wave & 1;             // 0..1 : 32-col group
  const int lb  = blockIdx.x;          // 0..511
  const int xcd = lb & 7;
  const int sl  = lb >> 3;             // 0..63
  const int bx  = sl & 15;             // col-block 0..15 (64-wide)
  const int by  = xcd * 4 + (sl >> 4); // row-strip 0..31 (128-tall)
  const int row0 = by * BM;
  const int col0 = bx * BN;
  const short* Ag = Xb + (size_t)row0 * KTOT;
  const short* Bg = Wb + (size_t)col0 * KTOT;
  const int frag_m = lane & 15;
  const int sel = lane >> 4;           // k-quarter within a K=32 sub-step
  floatx4 acc[2][2] = {};

  // staging: A tile = 1024 chunks of 16 B -> thread owns {tid, tid+512};
  // B tile = 512 chunks -> thread owns chunk tid. chunk c: row r = c>>3,
  // slot p = c&7, logical source chunk l = p ^ (r&7). LDS dest per wave =
  // uniform base + lane*16 B (global_load_lds rule).
  int soffA[2], ldstA[2];
  #pragma unroll
  for (int q = 0; q < 2; ++q) {
    int c = tid + q * 512;
    soffA[q] = (c >> 3) * KTOT + ((c & 7) ^ ((c >> 3) & 7)) * 8;
    ldstA[q] = c * 8;
  }
  const int soffB = (tid >> 3) * KTOT + ((tid & 7) ^ ((tid >> 3) & 7)) * 8;
  const int ldstB = tid * 8;

  // prologue: stage tiles 0 and 1 (3 loads per thread per tile)
  #pragma unroll
  for (int t = 0; t < 2; ++t) {
    load_lds16(Ag + soffA[0] + t * BK, &As[t][ldstA[0]]);
    load_lds16(Ag + soffA[1] + t * BK, &As[t][ldstA[1]]);
    load_lds16(Bg + soffB    + t * BK, &Bs[t][ldstB]);
  }

#define GSTEP(CUR, KT_PRE, DO_PRE, WAITIMM)                                   \
  {                                                                           \
    __builtin_amdgcn_s_waitcnt(WAITIMM);                                      \
    __builtin_amdgcn_s_barrier();                                             \
    _Pragma("unroll")                                                         \
    for (int s = 0; s < 2; ++s) {                                             \
      short8 af[2], bfr[2];                                                   \
      _Pragma("unroll")                                                       \
      for (int i = 0; i < 2; ++i) {                                           \
        int r = wr * 32 + i * 16 + frag_m;                                    \
        int p = (s * 4 + sel) ^ (r & 7);                                      \
        af[i] = *(const short8*)&As[CUR][r * BK + p * 8];                     \
      }                                                                       \
      _Pragma("unroll")                                                       \
      for (int j = 0; j < 2; ++j) {                                           \
        int r = wc * 32 + j * 16 + frag_m;                                    \
        int p = (s * 4 + sel) ^ (r & 7);                                      \
        bfr[j] = *(const short8*)&Bs[CUR][r * BK + p * 8];                    \
      }                                                                       \
      _Pragma("unroll")                                                       \
      for (int i = 0; i < 2; ++i)                                             \
        _Pragma("unroll")                                                     \
        for (int j = 0; j < 2; ++j)                                           \
          acc[i][j] = __builtin_amdgcn_mfma_f32_16x16x32_bf16(                \
              af[i], bfr[j], acc[i][j], 0, 0, 0);                             \
    }                                                                         \
    __builtin_amdgcn_s_barrier();                                             \
    if (DO_PRE) {                                                             \
      load_lds16(Ag + soffA[0] + (KT_PRE), &As[CUR][ldstA[0]]);               \
      load_lds16(Ag + soffA[1] + (KT_PRE), &As[CUR][ldstA[1]]);               \
      load_lds16(Bg + soffB    + (KT_PRE), &Bs[CUR][ldstB]);                  \
    }                                                                         \
  }

  for (int t = 0; t < 23; ++t) {       // step pairs (2t, 2t+1): steps 0..45
    GSTEP(0, (2 * t + 2) * BK, 1, WAIT_VM3);
    GSTEP(1, (2 * t + 3) * BK, 1, WAIT_VM3);
  }
  GSTEP(0, 0, 0, WAIT_VM3);            // step 46 (tile 47 still in flight)
  GSTEP(1, 0, 0, WAIT_VM0);            // step 47: drain
#undef GSTEP

  // epilogue: column sum/sumsq partials (no bias), bf16 Y write.
  // colred[4 wr-groups][sum|sq][64 cols] = 2 KB, aliased into As[0]
  // (dead: last read at step 46; step 47's barrier passed by all waves).
  float* colred = (float*)&As[0][0];
  float sv[2] = {0.f, 0.f}, sq[2] = {0.f, 0.f};
  #pragma unroll
  for (int j = 0; j < 2; ++j)
    #pragma unroll
    for (int i = 0; i < 2; ++i)
      #pragma unroll
      for (int r = 0; r < 4; ++r) {
        float v = acc[i][j][r];
        sv[j] += v; sq[j] += v * v;
      }
  #pragma unroll
  for (int j = 0; j < 2; ++j) {        // fold 4 sel-groups sharing a column
    sv[j] += __shfl_xor(sv[j], 16, 64); sv[j] += __shfl_xor(sv[j], 32, 64);
    sq[j] += __shfl_xor(sq[j], 16, 64); sq[j] += __shfl_xor(sq[j], 32, 64);
  }
  if (sel == 0) {
    #pragma unroll
    for (int j = 0; j < 2; ++j) {
      int cc = wc * 32 + j * 16 + frag_m;
      colred[(wr * 2 + 0) * 64 + cc] = sv[j];
      colred[(wr * 2 + 1) * 64 + cc] = sq[j];
    }
  }
  // write Y (un-normalized, bf16) while colred settles
  #pragma unroll
  for (int j = 0; j < 2; ++j) {
    int gc = col0 + wc * 32 + j * 16 + frag_m;
    #pragma unroll
    for (int i = 0; i < 2; ++i) {
      int gr = row0 + wr * 32 + i * 16 + sel * 4;
      #pragma unroll
      for (int r = 0; r < 4; ++r)
        Yb[(size_t)(gr + r) * OUTF + gc] = (unsigned short)f2bf(acc[i][j][r]);
    }
  }
  __syncthreads();
  if (tid < BN) {
    float s0 = colred[0 * 64 + tid] + colred[2 * 64 + tid]
             + colred[4 * 64 + tid] + colred[6 * 64 + tid];
    float s1 = colred[1 * 64 + tid] + colred[3 * 64 + tid]
             + colred[5 * 64 + tid] + colred[7 * 64 + tid];
    psum[(size_t)by * OUTF + col0 + tid] = s0;
    psq [(size_t)by * OUTF + col0 + tid] = s1;
  }
}

// ---- 3. fused finalize + BN apply (bf16 Y in -> f32 out) -------------------
__global__ void bn_fused(const float* __restrict__ psum, const float* __restrict__ psq,
                         const float* __restrict__ gamma, const float* __restrict__ beta,
                         const unsigned short* __restrict__ Yb,
                         float* __restrict__ out) {
  __shared__ float sc[32], sh[32];
  const int c0 = blockIdx.x * 32;
  const int t = threadIdx.x;
  if (t < 32) {
    float s = 0.f, s2 = 0.f;
    #pragma unroll 8
    for (int p = 0; p < 32; ++p) {
      s  += psum[p * OUTF + c0 + t];
      s2 += psq [p * OUTF + c0 + t];
    }
    float mean = s * (1.0f / B_ROWS);
    float var  = s2 * (1.0f / B_ROWS) - mean * mean;
    float scale = gamma[c0 + t] * rsqrtf(var + BN_EPS);
    sc[t] = scale;
    sh[t] = beta[c0 + t] - mean * scale;
  }
  __syncthreads();
  const int sl8 = t & 3;          // which 8-col slice of the 32
  const int rr  = t >> 2;         // 64 rows per sweep
  const int row0 = blockIdx.y * 256;
  float s_[8], h_[8];
  #pragma unroll
  for (int e = 0; e < 8; ++e) { s_[e] = sc[sl8 * 8 + e]; h_[e] = sh[sl8 * 8 + e]; }
  float4* O4 = (float4*)out;
  #pragma unroll
  for (int it = 0; it < 4; ++it) {
    int row = row0 + it * 64 + rr;
    short8 v = *(const short8*)&Yb[(size_t)row * OUTF + c0 + sl8 * 8];
    float4 o0, o1;
    o0.x = bf2f((unsigned short)v[0]) * s_[0] + h_[0];
    o0.y = bf2f((unsigned short)v[1]) * s_[1] + h_[1];
    o0.z = bf2f((unsigned short)v[2]) * s_[2] + h_[2];
    o0.w = bf2f((unsigned short)v[3]) * s_[3] + h_[3];
    o1.x = bf2f((unsigned short)v[4]) * s_[4] + h_[4];
    o1.y = bf2f((unsigned short)v[5]) * s_[5] + h_[5];
    o1.z = bf2f((unsigned short)v[6]) * s_[6] + h_[6];
    o1.w = bf2f((unsigned short)v[7]) * s_[7] + h_[7];
    size_t fi = (size_t)row * 256 + (c0 >> 2) + sl8 * 2;
    O4[fi]     = o0;
    O4[fi + 1] = o1;
  }
}

extern "C" void kernel_launch(void* const* d_in, const int* in_sizes, int n_in,
                              void* d_out, int out_size, void* d_ws, size_t ws_size,
                              hipStream_t stream) {
  const float* x     = (const float*)d_in[0];
  const float* c1    = (const float*)d_in[1];
  const float* c2    = (const float*)d_in[2];
  const float* c3    = (const float*)d_in[3];
  // d_in[4] = bias: unused — per-column constant cancels exactly in BatchNorm
  const float* gamma = (const float*)d_in[5];
  const float* beta  = (const float*)d_in[6];
  float* out = (float*)d_out;
  char* ws = (char*)d_ws;

  short* Xb            = (short*)(ws);                 // 25,165,824 B
  short* Wb            = (short*)(ws + 25165824);      //  6,291,456 B
  unsigned short* Yb   = (unsigned short*)(ws + 31457280);  // 8,388,608 B
  float* psum          = (float*)(ws + 39845888);      //    128 KB
  float* psq           = (float*)(ws + 39976960);      //    128 KB

  prep_all<<<5120, 256, 0, stream>>>((const float4*)x, (const float4*)c1,
                                     (const float4*)c2, (const float4*)c3,
                                     Xb, Wb);

  gemm_poly<<<512, 512, 0, stream>>>(Xb, Wb, Yb, psum, psq);

  dim3 bgrid(OUTF / 32, B_ROWS / 256);                 // (32, 16) = 512 blocks
  bn_fused<<<bgrid, 256, 0, stream>>>(psum, psq, gamma, beta, Yb, out);
}

// Round 8
// 124.044 us; speedup vs baseline: 1.0518x; 1.0518x over previous
//
#include <hip/hip_runtime.h>
#include <stdint.h>

#define B_ROWS 4096
#define OUTF   1024
#define INF    1024
#define KTOT   3072          // 3 * 1024
#define BN_EPS 1e-5f
#define BM 128
#define BN 128
#define BK 64
#define NSTEP (KTOT / BK)    // 48

typedef short  short8  __attribute__((ext_vector_type(8)));
typedef float  floatx4 __attribute__((ext_vector_type(4)));

struct alignas(8) s4 { short x, y, z, w; };

// s_waitcnt SIMM16 (gfx9/gfx950): vmcnt[3:0]=imm[3:0], expcnt=imm[6:4],
// lgkmcnt=imm[11:8], vmcnt[5:4]=imm[15:14].
#define WAIT_VM4 0x0F74      // vmcnt(4)
#define WAIT_VM2 0x0F72      // vmcnt(2)
#define WAIT_VM0 0x0F70      // vmcnt(0)

__device__ __forceinline__ short f2bf(float f) {
  union { float f; uint32_t u; } cv; cv.f = f;
  uint32_t u = cv.u;
  uint32_t r = (u + 0x7fffu + ((u >> 16) & 1u)) >> 16;  // RNE
  return (short)r;
}

__device__ __forceinline__ void load_lds16(const void* g, void* l) {
  __builtin_amdgcn_global_load_lds(
      (const __attribute__((address_space(1))) uint32_t*)(uintptr_t)g,
      (__attribute__((address_space(3))) uint32_t*)(uint32_t)(uintptr_t)l,
      16, 0, 0);
}

// ---- 1. prep: x -> bf16 {x,x^2,x^3} (Xb), c1|c2|c3 -> bf16 Wb --------------
// bias skipped: a per-column constant shifts the batch mean and is cancelled
// exactly by BatchNorm (variance unaffected). [verified R6..R9]
__global__ void prep_all(const float4* __restrict__ x4,
                         const float4* __restrict__ c1, const float4* __restrict__ c2,
                         const float4* __restrict__ c3,
                         short* __restrict__ Xb, short* __restrict__ Wb) {
  int b = blockIdx.x;
  if (b < 4096) {
    int idx = b * 256 + threadIdx.x;           // 1,048,576 float4 of x
    float4 v = x4[idx];
    int row = idx >> 8;
    int c   = (idx & 255) << 2;
    size_t base = (size_t)row * KTOT + c;
    s4 p1 = { f2bf(v.x), f2bf(v.y), f2bf(v.z), f2bf(v.w) };
    float ax = v.x * v.x, ay = v.y * v.y, az = v.z * v.z, aw = v.w * v.w;
    s4 p2 = { f2bf(ax), f2bf(ay), f2bf(az), f2bf(aw) };
    s4 p3 = { f2bf(ax * v.x), f2bf(ay * v.y), f2bf(az * v.z), f2bf(aw * v.w) };
    *(s4*)&Xb[base]        = p1;
    *(s4*)&Xb[base + 1024] = p2;
    *(s4*)&Xb[base + 2048] = p3;
  } else {
    int idx = (b - 4096) * 256 + threadIdx.x;  // 262,144 float4 per weight
    int row = idx >> 8;
    int c   = (idx & 255) << 2;
    size_t base = (size_t)row * KTOT + c;
    float4 a = c1[idx], bb = c2[idx], d = c3[idx];
    s4 p1 = { f2bf(a.x),  f2bf(a.y),  f2bf(a.z),  f2bf(a.w)  };
    s4 p2 = { f2bf(bb.x), f2bf(bb.y), f2bf(bb.z), f2bf(bb.w) };
    s4 p3 = { f2bf(d.x),  f2bf(d.y),  f2bf(d.z),  f2bf(d.w)  };
    *(s4*)&Wb[base]        = p1;
    *(s4*)&Wb[base + 1024] = p2;
    *(s4*)&Wb[base + 2048] = p3;
  }
}

// ---- 2. GEMM 128x128, BK=64, 1024 threads (16 waves), quad-buffer ----------
// VERIFIED BEST (123.36 us session baseline; ~1120 TF = 45% dense peak).
// Structure-sweep results (fill-corrected "ours"):
//   R0 16w/128^2/quad-buf vmcnt(4): 39.6 us   <- this kernel
//   R1  4w/128^2 (1 wave/SIMD):     ~42       (TLP loss)
//   R5 in-gemm powers (no Xb):      39.3      (prep saving == VALU cost)
//   R6  8w/128^2 + bf16-Y:          39.3      (LDS-traffic cut == TLP loss)
//   R7  8w/128x64, 2 blk/CU dbuf:   ~43       (staging up, pipeline shallower)
// Conclusion: at this geometry (256 blocks of 128^2 = exactly 1/CU, the only
// full-chip tiling for M=4096,N=1024), this schedule is the optimum found;
// prep and bn sit at their HBM floors; remaining dur is harness poison fills.
// Wave grid 4x4, each wave 32x32 (2x2 MFMA frags). Per thread: 1 A-chunk +
// 1 B-chunk per tile; 3-deep prefetch => 6 loads in flight, wait vmcnt(4)
// per step. LDS 4x(16+16) KB = 128 KB. XOR chunk swizzle: physical 16B slot
// p of row r holds logical chunk p ^ (r & 7) -> 0 conflicts [R2..R9].
__global__ __launch_bounds__(1024, 4) void gemm_poly(
    const short* __restrict__ Xb, const short* __restrict__ Wb,
    float* __restrict__ Y, float* __restrict__ psum, float* __restrict__ psq) {
  __shared__ __align__(16) short As[4][BM * BK];   // 4 x 16 KB
  __shared__ __align__(16) short Bs[4][BN * BK];   // 4 x 16 KB  (128 KB total)
  const int tid  = threadIdx.x;
  const int lane = tid & 63;
  const int wave = tid >> 6;           // 0..15
  const int wr = wave >> 2;            // 0..3 : 32-row group
  const int wc = wave & 3;             // 0..3 : 32-col group
  const int lb  = blockIdx.x;
  const int xcd = lb & 7;
  const int sl  = lb >> 3;             // 0..31
  const int bx  = sl & 7;              // col-block 0..7
  const int by  = xcd * 4 + (sl >> 3); // row-strip 0..31
  const int row0 = by * BM;
  const int col0 = bx * BN;
  const short* Ag = Xb + (size_t)row0 * KTOT;
  const short* Bg = Wb + (size_t)col0 * KTOT;
  const int frag_m = lane & 15;
  const int sel = lane >> 4;           // k-quarter within a K=32 sub-step
  floatx4 acc[2][2] = {};

  // staging: thread tid owns chunk tid of the A tile and chunk tid of the B
  // tile (1024 chunks of 16 B each). row r = tid>>3, slot p = tid&7,
  // logical source chunk l = p ^ (r & 7).
  const int soff = (tid >> 3) * KTOT + ((tid & 7) ^ ((tid >> 3) & 7)) * 8;
  const int ldst = tid * 8;

  // prologue: stage tiles 0,1,2 (2 loads per thread per tile, in order)
  #pragma unroll
  for (int t = 0; t < 3; ++t) {
    load_lds16(Ag + soff + t * BK, &As[t][ldst]);
    load_lds16(Bg + soff + t * BK, &Bs[t][ldst]);
  }

#define GSTEP(CUR, PRE, KT_PRE, DO_PRE, WAITIMM)                              \
  {                                                                           \
    __builtin_amdgcn_s_waitcnt(WAITIMM);                                      \
    __builtin_amdgcn_s_barrier();                                             \
    if (DO_PRE) {                                                             \
      load_lds16(Ag + soff + (KT_PRE), &As[PRE][ldst]);                       \
      load_lds16(Bg + soff + (KT_PRE), &Bs[PRE][ldst]);                       \
    }                                                                         \
    _Pragma("unroll")                                                         \
    for (int s = 0; s < 2; ++s) {                                             \
      short8 af[2], bfr[2];                                                   \
      _Pragma("unroll")                                                       \
      for (int i = 0; i < 2; ++i) {                                           \
        int r = wr * 32 + i * 16 + frag_m;                                    \
        int p = (s * 4 + sel) ^ (r & 7);                                      \
        af[i] = *(const short8*)&As[CUR][r * BK + p * 8];                     \
      }                                                                       \
      _Pragma("unroll")                                                       \
      for (int j = 0; j < 2; ++j) {                                           \
        int r = wc * 32 + j * 16 + frag_m;                                    \
        int p = (s * 4 + sel) ^ (r & 7);                                      \
        bfr[j] = *(const short8*)&Bs[CUR][r * BK + p * 8];                    \
      }                                                                       \
      _Pragma("unroll")                                                       \
      for (int i = 0; i < 2; ++i)                                             \
        _Pragma("unroll")                                                     \
        for (int j = 0; j < 2; ++j)                                           \
          acc[i][j] = __builtin_amdgcn_mfma_f32_16x16x32_bf16(                \
              af[i], bfr[j], acc[i][j], 0, 0, 0);                             \
    }                                                                         \
  }

  for (int t4 = 0; t4 < 44; t4 += 4) {         // steps 0..43 (prefetch s+3)
    GSTEP(0, 3, (t4 + 3) * BK, 1, WAIT_VM4);
    GSTEP(1, 0, (t4 + 4) * BK, 1, WAIT_VM4);
    GSTEP(2, 1, (t4 + 5) * BK, 1, WAIT_VM4);
    GSTEP(3, 2, (t4 + 6) * BK, 1, WAIT_VM4);
  }
  GSTEP(0, 3, 47 * BK, 1, WAIT_VM4);           // step 44, prefetch tile 47
  GSTEP(1, 0, 0, 0, WAIT_VM4);                 // step 45 (tiles 46,47 inflight)
  GSTEP(2, 0, 0, 0, WAIT_VM2);                 // step 46 (tile 47 in flight)
  GSTEP(3, 0, 0, 0, WAIT_VM0);                 // step 47: drain everything
#undef GSTEP

  // epilogue: column sum/sumsq partials (no bias), un-normalized Y write.
  // colred[4 wr-groups][sum|sq][128 cols] = 4 KB, aliased into As[0]
  // (dead: last read step 44; 3 barriers since).
  float* colred = (float*)&As[0][0];
  float sv[2] = {0.f, 0.f}, sq[2] = {0.f, 0.f};
  #pragma unroll
  for (int j = 0; j < 2; ++j)
    #pragma unroll
    for (int i = 0; i < 2; ++i)
      #pragma unroll
      for (int r = 0; r < 4; ++r) {
        float v = acc[i][j][r];
        sv[j] += v; sq[j] += v * v;
      }
  #pragma unroll
  for (int j = 0; j < 2; ++j) {        // fold 4 sel-groups sharing a column
    sv[j] += __shfl_xor(sv[j], 16, 64); sv[j] += __shfl_xor(sv[j], 32, 64);
    sq[j] += __shfl_xor(sq[j], 16, 64); sq[j] += __shfl_xor(sq[j], 32, 64);
  }
  if (sel == 0) {
    #pragma unroll
    for (int j = 0; j < 2; ++j) {
      int cc = wc * 32 + j * 16 + frag_m;
      colred[(wr * 2 + 0) * 128 + cc] = sv[j];
      colred[(wr * 2 + 1) * 128 + cc] = sq[j];
    }
  }
  // write Y (un-normalized) while colred settles
  #pragma unroll
  for (int j = 0; j < 2; ++j) {
    int gc = col0 + wc * 32 + j * 16 + frag_m;
    #pragma unroll
    for (int i = 0; i < 2; ++i) {
      int gr = row0 + wr * 32 + i * 16 + sel * 4;
      #pragma unroll
      for (int r = 0; r < 4; ++r)
        Y[(size_t)(gr + r) * OUTF + gc] = acc[i][j][r];
    }
  }
  __syncthreads();
  if (tid < BN) {
    float s0 = colred[0 * 128 + tid] + colred[2 * 128 + tid]
             + colred[4 * 128 + tid] + colred[6 * 128 + tid];
    float s1 = colred[1 * 128 + tid] + colred[3 * 128 + tid]
             + colred[5 * 128 + tid] + colred[7 * 128 + tid];
    psum[(size_t)by * OUTF + col0 + tid] = s0;
    psq [(size_t)by * OUTF + col0 + tid] = s1;
  }
}

// ---- 3. fused finalize + BN apply ------------------------------------------
__global__ void bn_fused(const float* __restrict__ psum, const float* __restrict__ psq,
                         const float* __restrict__ gamma, const float* __restrict__ beta,
                         float* __restrict__ Y) {
  __shared__ float sc[32], sh[32];
  const int c0 = blockIdx.x * 32;
  const int t = threadIdx.x;
  if (t < 32) {
    float s = 0.f, s2 = 0.f;
    #pragma unroll 8
    for (int p = 0; p < 32; ++p) {
      s  += psum[p * OUTF + c0 + t];
      s2 += psq [p * OUTF + c0 + t];
    }
    float mean = s * (1.0f / B_ROWS);
    float var  = s2 * (1.0f / B_ROWS) - mean * mean;
    float scale = gamma[c0 + t] * rsqrtf(var + BN_EPS);
    sc[t] = scale;
    sh[t] = beta[c0 + t] - mean * scale;
  }
  __syncthreads();
  const int f4c = t & 7;          // 8 float4 per 32-col slice
  const int rr  = t >> 3;         // 32 rows per sweep
  const int row0 = blockIdx.y * 256;
  float4* Y4 = (float4*)Y;
  const int cb = f4c * 4;
  float s0 = sc[cb], s1 = sc[cb+1], s2 = sc[cb+2], s3 = sc[cb+3];
  float h0 = sh[cb], h1 = sh[cb+1], h2 = sh[cb+2], h3 = sh[cb+3];
  #pragma unroll
  for (int it = 0; it < 8; ++it) {
    int row = row0 + it * 32 + rr;
    size_t idx = (size_t)row * 256 + (c0 >> 2) + f4c;
    float4 v = Y4[idx];
    v.x = v.x * s0 + h0; v.y = v.y * s1 + h1;
    v.z = v.z * s2 + h2; v.w = v.w * s3 + h3;
    Y4[idx] = v;
  }
}

extern "C" void kernel_launch(void* const* d_in, const int* in_sizes, int n_in,
                              void* d_out, int out_size, void* d_ws, size_t ws_size,
                              hipStream_t stream) {
  const float* x     = (const float*)d_in[0];
  const float* c1    = (const float*)d_in[1];
  const float* c2    = (const float*)d_in[2];
  const float* c3    = (const float*)d_in[3];
  // d_in[4] = bias: unused — per-column constant cancels exactly in BatchNorm
  const float* gamma = (const float*)d_in[5];
  const float* beta  = (const float*)d_in[6];
  float* out = (float*)d_out;
  char* ws = (char*)d_ws;

  short* Xb   = (short*)(ws);                          // 25,165,824 B
  short* Wb   = (short*)(ws + 25165824);               //  6,291,456 B
  float* psum = (float*)(ws + 31457280);               //    128 KB
  float* psq  = (float*)(ws + 31588352);               //    128 KB

  prep_all<<<5120, 256, 0, stream>>>((const float4*)x, (const float4*)c1,
                                     (const float4*)c2, (const float4*)c3,
                                     Xb, Wb);

  gemm_poly<<<256, 1024, 0, stream>>>(Xb, Wb, out, psum, psq);

  dim3 bgrid(OUTF / 32, B_ROWS / 256);                 // (32, 16) = 512 blocks
  bn_fused<<<bgrid, 256, 0, stream>>>(psum, psq, gamma, beta, out);
}